// Round 14
// baseline (309.847 us; speedup 1.0000x reference)
//
#include <hip/hip_runtime.h>
#include <hip/hip_bf16.h>

#define NN 100000
#define NE 3200000
#define INC 256
#define HID 64
#define OUTC 2
#define EPSV 1e-5f

#define SCAN_CHUNK 1024
#define NBLK ((NN + SCAN_CHUNK - 1) / SCAN_CHUNK)   // 98

#define NBUCK 128
#define BCAP  26000          // mean 25000, sigma ~157 -> +6.4 sigma margin
#define BIN_CHUNK 4096
#define BIN_K 16             // edges per thread (256 threads * 16 = 4096)
#define BIN_GRID ((NE + BIN_CHUNK - 1) / BIN_CHUNK)  // 782

#define NQUART 25000         // dst quarter (2 ch-halves x 4 dst-quarters = 8 cohorts)

typedef short short8 __attribute__((ext_vector_type(8)));
typedef float f32x4 __attribute__((ext_vector_type(4)));

static __device__ __forceinline__ float bf2f(unsigned short u) {
    return __uint_as_float((unsigned)u << 16);
}
static __device__ __forceinline__ unsigned short f2bf(float f) {
    __hip_bfloat16 hb = __float2bfloat16(f);   // RNE
    return *(unsigned short*)&hb;
}

// ---------------- bin: partition edges into 128 dst-range buckets ----------------
// Packed entry: (dloc<<17) | src  (src < 2^17, dloc < 800 < 2^10).
__global__ __launch_bounds__(256) void bin_kernel(const int* __restrict__ src,
                                                  const int* __restrict__ dst,
                                                  int* __restrict__ gtail,
                                                  unsigned int* __restrict__ pbuf) {
    __shared__ int bcnt[NBUCK], bbase[NBUCK];
    int t = threadIdx.x;
    if (t < NBUCK) bcnt[t] = 0;
    __syncthreads();
    int base = blockIdx.x * BIN_CHUNK;
    int s[BIN_K], d[BIN_K], sl[BIN_K], bk[BIN_K];
#pragma unroll
    for (int r = 0; r < BIN_K; r++) {
        int i = base + r * 256 + t;
        bool v = i < NE;
        s[r] = v ? src[i] : 0;
        d[r] = v ? dst[i] : 0;
        bk[r] = (int)(((unsigned)d[r] * (unsigned)NBUCK) / (unsigned)NN);
        sl[r] = v ? atomicAdd(&bcnt[bk[r]], 1) : 0;
    }
    __syncthreads();
    if (t < NBUCK) bbase[t] = bcnt[t] ? atomicAdd(&gtail[t], bcnt[t]) : 0;
    __syncthreads();
#pragma unroll
    for (int r = 0; r < BIN_K; r++) {
        int i = base + r * 256 + t;
        if (i < NE) {
            int b = bk[r];
            int nbase = (b * NN + NBUCK - 1) >> 7;
            pbuf[(size_t)b * BCAP + bbase[b] + sl[r]] =
                ((unsigned)(d[r] - nbase) << 17) | (unsigned)s[r];
        }
    }
}

// ---------------- hist2: per-bucket LDS node histogram -> cnt ----------------
__global__ __launch_bounds__(256) void hist2_kernel(const unsigned int* __restrict__ pbuf,
                                                    const int* __restrict__ gtail,
                                                    int* __restrict__ cnt) {
    __shared__ int h[800];
    int b = blockIdx.x, t = threadIdx.x;
    int nb = (b * NN + NBUCK - 1) >> 7;
    int ne_ = ((b + 1) * NN + NBUCK - 1) >> 7;
    int range = ne_ - nb;
    for (int i = t; i < range; i += 256) h[i] = 0;
    __syncthreads();
    int ecnt = gtail[b];
    const unsigned int* p = pbuf + (size_t)b * BCAP;
    for (int i = t; i < ecnt; i += 256) atomicAdd(&h[p[i] >> 17], 1);
    __syncthreads();
    for (int i = t; i < range; i += 256) cnt[nb + i] = h[i];
}

// ---------------- scan step 1: per-chunk totals ----------------
__global__ void scan_btot_kernel(const int* __restrict__ cnt, int* __restrict__ btot) {
    __shared__ int red[4];
    int b = blockIdx.x, t = threadIdx.x;
    int base = b * SCAN_CHUNK;
    int v = 0;
    for (int j = t; j < SCAN_CHUNK; j += 256) {
        int idx = base + j;
        v += (idx < NN) ? cnt[idx] : 0;
    }
    for (int o = 32; o; o >>= 1) v += __shfl_xor(v, o);
    int wave = t >> 6, lane = t & 63;
    if (lane == 0) red[wave] = v;
    __syncthreads();
    if (t == 0) btot[b] = red[0] + red[1] + red[2] + red[3];
}

// ---------------- scan step 2: exclusive scan of chunk totals ----------------
__global__ void scan_boff_kernel(const int* __restrict__ btot, int* __restrict__ boff) {
    __shared__ int wtot[2];
    int t = threadIdx.x;           // 128 threads
    int lane = t & 63, wave = t >> 6;
    int v = (t < NBLK) ? btot[t] : 0;
    int s = v;
    for (int o = 1; o < 64; o <<= 1) {
        int u = __shfl_up(s, o);
        if (lane >= o) s += u;
    }
    if (lane == 63) wtot[wave] = s;
    __syncthreads();
    int add = (wave == 1) ? wtot[0] : 0;
    if (t < NBLK) boff[t] = s - v + add;   // exclusive prefix
}

// ---------------- scan step 3: full rowptr + dinv ----------------
__global__ void scan_rowptr_kernel(const int* __restrict__ cnt, const int* __restrict__ boff,
                                   int* __restrict__ rowptr, float* __restrict__ dinv) {
    __shared__ int wsum[4];
    int b = blockIdx.x, t = threadIdx.x;
    int lane = t & 63, wave = t >> 6;
    int idx = b * SCAN_CHUNK + t * 4;
    int c0 = (idx + 0 < NN) ? cnt[idx + 0] : 0;
    int c1 = (idx + 1 < NN) ? cnt[idx + 1] : 0;
    int c2 = (idx + 2 < NN) ? cnt[idx + 2] : 0;
    int c3 = (idx + 3 < NN) ? cnt[idx + 3] : 0;
    int local = c0 + c1 + c2 + c3;
    int s = local;
    for (int o = 1; o < 64; o <<= 1) {
        int u = __shfl_up(s, o);
        if (lane >= o) s += u;
    }
    if (lane == 63) wsum[wave] = s;
    __syncthreads();
    if (t == 0) {
        int run = 0;
        for (int w = 0; w < 4; w++) { int x = wsum[w]; wsum[w] = run; run += x; }
    }
    __syncthreads();
    int start = boff[b] + wsum[wave] + (s - local);
    if (idx + 0 < NN) { rowptr[idx + 0] = start;                dinv[idx + 0] = rsqrtf((float)(c0 + 1)); }
    if (idx + 1 < NN) { rowptr[idx + 1] = start + c0;           dinv[idx + 1] = rsqrtf((float)(c1 + 1)); }
    if (idx + 2 < NN) { rowptr[idx + 2] = start + c0 + c1;      dinv[idx + 2] = rsqrtf((float)(c2 + 1)); }
    if (idx + 3 < NN) { rowptr[idx + 3] = start + c0 + c1 + c2; dinv[idx + 3] = rsqrtf((float)(c3 + 1)); }
    if (b == 0 && t == 0) rowptr[NN] = NE;
}

// ---------------- scatter2: per-bucket CSR fill (rowptr staged in LDS) ----------------
__global__ __launch_bounds__(256) void scatter2_kernel(const unsigned int* __restrict__ pbuf,
                                                       const int* __restrict__ gtail,
                                                       const int* __restrict__ rowptr,
                                                       int* __restrict__ e_src) {
    __shared__ int rp[800], fill[800];
    int b = blockIdx.x, t = threadIdx.x;
    int nb = (b * NN + NBUCK - 1) >> 7;
    int ne_ = ((b + 1) * NN + NBUCK - 1) >> 7;
    int range = ne_ - nb;
    for (int i = t; i < range; i += 256) {
        rp[i] = rowptr[nb + i];
        fill[i] = 0;
    }
    __syncthreads();
    int ecnt = gtail[b];
    const unsigned int* p = pbuf + (size_t)b * BCAP;
    for (int i = t; i < ecnt; i += 256) {
        unsigned int k = p[i];
        int loc = k >> 17;
        int pos = rp[loc] + atomicAdd(&fill[loc], 1);
        e_src[pos] = (int)(k & 0x1FFFFu);
    }
}

// ---------------- wprep: W1 [256][64] fp32 -> Wtb [64][256] bf16 (transposed) ----------------
__global__ __launch_bounds__(256) void wprep_kernel(const float* __restrict__ W1,
                                                    unsigned short* __restrict__ Wtb) {
    int t = blockIdx.x * 256 + threadIdx.x;    // 16384 threads
    int c = t & 63;
    int k = t >> 6;
    Wtb[c * 256 + k] = f2bf(W1[k * 64 + c]);
}

// ---------------- GEMM1 (MFMA): xw1h[half][N][32] = bf16( dinv .* (x @ W1) ) ----------------
// R14: W read directly from global (32KB, L1/L2-resident; B-frag reads are
// full-line: for fixed kk, 16 rows x 64B). LDS = x tile only (17KB) -> high
// occupancy, single sync.
#define G1_ROWS 32
#define LDP 264
__global__ __launch_bounds__(256) void gemm1_kernel(const float* __restrict__ x,
                                                    const unsigned short* __restrict__ Wtb,
                                                    const float* __restrict__ dinv,
                                                    unsigned short* __restrict__ xw1h) {
    __shared__ unsigned short xt[G1_ROWS * LDP];   // 16896 B
    int t = threadIdx.x;
    size_t base = (size_t)blockIdx.x * G1_ROWS;

    const float4* xg = (const float4*)(x + base * INC);
#pragma unroll
    for (int ii = 0; ii < 8; ii++) {
        int idx4 = ii * 256 + t;
        float4 v = xg[idx4];
        int f = idx4 * 4;
        int row = f >> 8, k = f & 255;
        ushort4 u;
        u.x = f2bf(v.x); u.y = f2bf(v.y); u.z = f2bf(v.z); u.w = f2bf(v.w);
        *(ushort4*)(xt + row * LDP + k) = u;
    }
    __syncthreads();

    int lane = t & 63;
    int wave = t >> 6;
    int l15 = lane & 15;
    int hi = lane >> 4;
    int rgrp = wave & 1;          // row group: 16 rows
    int cgrp = wave >> 1;         // channel half: 32 channels
    const unsigned short* ap = xt + (rgrp * 16 + l15) * LDP;
    const unsigned short* bp0 = Wtb + (cgrp * 32 + l15) * 256;       // global, L1-hot
    const unsigned short* bp1 = bp0 + 16 * 256;
    f32x4 acc0 = {0.f, 0.f, 0.f, 0.f};
    f32x4 acc1 = {0.f, 0.f, 0.f, 0.f};
#pragma unroll
    for (int kk = 0; kk < 8; kk++) {
        int ko = kk * 32 + hi * 8;
        short8 a  = *(const short8*)(ap + ko);
        short8 b0 = *(const short8*)(bp0 + ko);
        short8 b1 = *(const short8*)(bp1 + ko);
        acc0 = __builtin_amdgcn_mfma_f32_16x16x32_bf16(a, b0, acc0, 0, 0, 0);
        acc1 = __builtin_amdgcn_mfma_f32_16x16x32_bf16(a, b1, acc1, 0, 0, 0);
    }
    // D: col = lane&15, row = (lane>>4)*4 + i
    unsigned short* ph = xw1h + (size_t)cgrp * NN * 32;
#pragma unroll
    for (int i = 0; i < 4; i++) {
        int grow = (int)base + rgrp * 16 + hi * 4 + i;
        float dv = dinv[grow];
        ph[(size_t)grow * 32 + l15]      = f2bf(acc0[i] * dv);
        ph[(size_t)grow * 32 + l15 + 16] = f2bf(acc1[i] * dv);
    }
}

// ---------------- agg1: 8-lane group per node, full-line gathers (R11 config) ----------------
// cohort = blockIdx&7 -> (h = channel half, dq = dst quarter). Group of 8
// lanes gathers one 64B half-plane row per edge (ushort4/lane = 4 channels);
// register accumulation; unroll x4 (R13's x8 cost occupancy, regressed).
__global__ __launch_bounds__(256) void agg1_kernel(const unsigned short* __restrict__ xw1h,
                                                   const int* __restrict__ rowptr,
                                                   const int* __restrict__ e_src,
                                                   const float* __restrict__ dinv,
                                                   const float* __restrict__ b1,
                                                   float* __restrict__ h1h,
                                                   float* __restrict__ sums1) {
    __shared__ float lsum[4][32], lsq[4][32];
    int t = threadIdx.x;
    int lane = t & 63;
    int wave = t >> 6;
    int grp = lane >> 3;          // node group within wave (8 groups)
    int cl = lane & 7;            // ushort4 slot: channels cl*4 .. cl*4+3
    int cohort = blockIdx.x & 7;
    int h = cohort & 1;           // channel half
    int dq = cohort >> 1;         // dst quarter
    const ushort4* plane = (const ushort4*)(xw1h + (size_t)h * NN * 32);
    float* hp = h1h + (size_t)h * NN * 32;
    float bb0 = b1[h * 32 + cl * 4 + 0];
    float bb1 = b1[h * 32 + cl * 4 + 1];
    float bb2 = b1[h * 32 + cl * 4 + 2];
    float bb3 = b1[h * 32 + cl * 4 + 3];
    int gid = ((blockIdx.x >> 3) * 4 + wave) * 8 + grp;   // 0..8191 per cohort
    int dlo = dq * NQUART;
    float ss0 = 0.f, ss1 = 0.f, ss2 = 0.f, ss3 = 0.f;
    float sq0 = 0.f, sq1 = 0.f, sq2 = 0.f, sq3 = 0.f;
    for (int d = dlo + gid; d < dlo + NQUART; d += 8192) {
        int beg = rowptr[d], end = rowptr[d + 1];
        float a0 = 0.f, a1 = 0.f, a2 = 0.f, a3 = 0.f;
        int e = beg;
        for (; e + 3 < end; e += 4) {          // 4 independent 64B line-gathers
            int s0 = e_src[e], s1 = e_src[e + 1], s2 = e_src[e + 2], s3 = e_src[e + 3];
            ushort4 u0 = plane[(size_t)s0 * 8 + cl];
            ushort4 u1 = plane[(size_t)s1 * 8 + cl];
            ushort4 u2 = plane[(size_t)s2 * 8 + cl];
            ushort4 u3 = plane[(size_t)s3 * 8 + cl];
            a0 += bf2f(u0.x) + bf2f(u1.x) + bf2f(u2.x) + bf2f(u3.x);
            a1 += bf2f(u0.y) + bf2f(u1.y) + bf2f(u2.y) + bf2f(u3.y);
            a2 += bf2f(u0.z) + bf2f(u1.z) + bf2f(u2.z) + bf2f(u3.z);
            a3 += bf2f(u0.w) + bf2f(u1.w) + bf2f(u2.w) + bf2f(u3.w);
        }
        for (; e < end; e++) {
            int s = e_src[e];
            ushort4 u = plane[(size_t)s * 8 + cl];
            a0 += bf2f(u.x); a1 += bf2f(u.y); a2 += bf2f(u.z); a3 += bf2f(u.w);
        }
        ushort4 us = plane[(size_t)d * 8 + cl];    // self-loop
        a0 += bf2f(us.x); a1 += bf2f(us.y); a2 += bf2f(us.z); a3 += bf2f(us.w);
        float dv = dinv[d];
        float h0 = a0 * dv + bb0;
        float h1v = a1 * dv + bb1;
        float h2 = a2 * dv + bb2;
        float h3 = a3 * dv + bb3;
        f32x4 hv = {h0, h1v, h2, h3};
        *(f32x4*)(hp + (size_t)d * 32 + cl * 4) = hv;
        ss0 += h0; sq0 += h0 * h0;
        ss1 += h1v; sq1 += h1v * h1v;
        ss2 += h2; sq2 += h2 * h2;
        ss3 += h3; sq3 += h3 * h3;
    }
    // stats: reduce across the 8 groups (stride-8 lanes share cl)
#pragma unroll
    for (int o = 8; o < 64; o <<= 1) {
        ss0 += __shfl_xor(ss0, o); sq0 += __shfl_xor(sq0, o);
        ss1 += __shfl_xor(ss1, o); sq1 += __shfl_xor(sq1, o);
        ss2 += __shfl_xor(ss2, o); sq2 += __shfl_xor(sq2, o);
        ss3 += __shfl_xor(ss3, o); sq3 += __shfl_xor(sq3, o);
    }
    if (grp == 0) {
        lsum[wave][cl * 4 + 0] = ss0; lsq[wave][cl * 4 + 0] = sq0;
        lsum[wave][cl * 4 + 1] = ss1; lsq[wave][cl * 4 + 1] = sq1;
        lsum[wave][cl * 4 + 2] = ss2; lsq[wave][cl * 4 + 2] = sq2;
        lsum[wave][cl * 4 + 3] = ss3; lsq[wave][cl * 4 + 3] = sq3;
    }
    __syncthreads();
    if (t < 32) {
        float S = lsum[0][t] + lsum[1][t] + lsum[2][t] + lsum[3][t];
        float Q = lsq[0][t] + lsq[1][t] + lsq[2][t] + lsq[3][t];
        atomicAdd(&sums1[h * 32 + t], S);
        atomicAdd(&sums1[64 + h * 32 + t], Q);
    }
}

// ---------------- gemm2: xw2' = dinv .* (relu(BN1(h1)) @ W2) ----------------
__global__ __launch_bounds__(256) void gemm2_kernel(const float* __restrict__ h1h,
                                                    const float* __restrict__ sums1,
                                                    const float* __restrict__ g1,
                                                    const float* __restrict__ be1,
                                                    const float* __restrict__ W2,
                                                    const float* __restrict__ dinv,
                                                    float* __restrict__ xw2) {
    int lane = threadIdx.x & 63;
    int row = blockIdx.x * 4 + (threadIdx.x >> 6);
    if (row >= NN) return;
    int c = lane;
    const float invn = 1.0f / (float)NN;
    float mu = sums1[c] * invn;
    float var = sums1[64 + c] * invn - mu * mu;
    float sc = g1[c] * rsqrtf(var + EPSV);
    float sh = be1[c] - mu * sc;
    float hv = h1h[(size_t)(c >> 5) * NN * 32 + (size_t)row * 32 + (c & 31)] * sc + sh;
    hv = fmaxf(hv, 0.f);
    float p0 = hv * W2[c * 2 + 0];
    float p1 = hv * W2[c * 2 + 1];
    for (int o = 32; o; o >>= 1) {
        p0 += __shfl_xor(p0, o);
        p1 += __shfl_xor(p1, o);
    }
    if (lane == 0) {
        float dv = dinv[row];
        xw2[(size_t)row * 2 + 0] = p0 * dv;
        xw2[(size_t)row * 2 + 1] = p1 * dv;
    }
}

// ---------------- agg2: 8-lane group per node, banked stats ----------------
__global__ __launch_bounds__(256) void agg2_kernel(const float* __restrict__ xw2,
                                                   const int* __restrict__ rowptr,
                                                   const int* __restrict__ e_src,
                                                   const float* __restrict__ dinv,
                                                   const float* __restrict__ b2,
                                                   float* __restrict__ z2,
                                                   float* __restrict__ sums2) {
    __shared__ float red[4][4];
    int t = threadIdx.x;
    int lane = t & 63;
    int wave = t >> 6;
    int gl = lane & 7;                       // lane within node-group
    int d = blockIdx.x * 32 + (t >> 3);      // grid sized so d < NN always
    int beg = rowptr[d], end = rowptr[d + 1];
    float a0 = 0.f, a1 = 0.f;
    int e = beg + gl;
    for (; e + 24 < end; e += 32) {          // 4 independent gathers in flight
        int s0 = e_src[e], s1 = e_src[e + 8], s2 = e_src[e + 16], s3 = e_src[e + 24];
        float2 v0 = *(const float2*)(xw2 + (size_t)s0 * 2);
        float2 v1 = *(const float2*)(xw2 + (size_t)s1 * 2);
        float2 v2 = *(const float2*)(xw2 + (size_t)s2 * 2);
        float2 v3 = *(const float2*)(xw2 + (size_t)s3 * 2);
        a0 += v0.x + v1.x + v2.x + v3.x;
        a1 += v0.y + v1.y + v2.y + v3.y;
    }
    for (; e < end; e += 8) {
        int s = e_src[e];
        float2 v = *(const float2*)(xw2 + (size_t)s * 2);
        a0 += v.x;
        a1 += v.y;
    }
    if (gl == 0) {                           // self-loop
        float2 sf = *(const float2*)(xw2 + (size_t)d * 2);
        a0 += sf.x;
        a1 += sf.y;
    }
    a0 += __shfl_xor(a0, 1); a1 += __shfl_xor(a1, 1);
    a0 += __shfl_xor(a0, 2); a1 += __shfl_xor(a1, 2);
    a0 += __shfl_xor(a0, 4); a1 += __shfl_xor(a1, 4);
    float dv = dinv[d];
    float z0 = a0 * dv + b2[0];
    float z1 = a1 * dv + b2[1];
    if (gl == 0) *(float2*)(z2 + (size_t)d * 2) = make_float2(z0, z1);
    float s0 = (gl == 0) ? z0 : 0.f;
    float s1 = (gl == 0) ? z1 : 0.f;
    float q0 = (gl == 0) ? z0 * z0 : 0.f;
    float q1 = (gl == 0) ? z1 * z1 : 0.f;
    for (int o = 8; o < 64; o <<= 1) {
        s0 += __shfl_xor(s0, o); s1 += __shfl_xor(s1, o);
        q0 += __shfl_xor(q0, o); q1 += __shfl_xor(q1, o);
    }
    if (lane == 0) { red[wave][0] = s0; red[wave][1] = s1; red[wave][2] = q0; red[wave][3] = q1; }
    __syncthreads();
    if (t < 4) {
        float v = red[0][t] + red[1][t] + red[2][t] + red[3][t];
        atomicAdd(&sums2[(blockIdx.x & 7) * 4 + t], v);   // 8 banks
    }
}

// ---------------- decoder: out = BN2(z2) @ Wd + bd (sums2 banked [8][4]) ----------------
__global__ __launch_bounds__(256) void decoder_kernel(const float* __restrict__ z2,
                                                      const float* __restrict__ sums2,
                                                      const float* __restrict__ g2,
                                                      const float* __restrict__ be2,
                                                      const float* __restrict__ Wd,
                                                      const float* __restrict__ bd,
                                                      float* __restrict__ out) {
    int g = blockIdx.x * 256 + threadIdx.x;
    int row = g >> 6;
    int c4 = (g & 63) * 4;
    float t0 = 0.f, t1 = 0.f, t2 = 0.f, t3 = 0.f;
#pragma unroll
    for (int bk = 0; bk < 8; bk++) {
        t0 += sums2[bk * 4 + 0]; t1 += sums2[bk * 4 + 1];
        t2 += sums2[bk * 4 + 2]; t3 += sums2[bk * 4 + 3];
    }
    const float invn = 1.0f / (float)NN;
    float mu0 = t0 * invn, mu1 = t1 * invn;
    float v0 = t2 * invn - mu0 * mu0;
    float v1 = t3 * invn - mu1 * mu1;
    float sc0 = g2[0] * rsqrtf(v0 + EPSV), sh0 = be2[0] - mu0 * sc0;
    float sc1 = g2[1] * rsqrtf(v1 + EPSV), sh1 = be2[1] - mu1 * sc1;
    float zb0 = z2[(size_t)row * 2 + 0] * sc0 + sh0;
    float zb1 = z2[(size_t)row * 2 + 1] * sc1 + sh1;
    float4 w0 = *(const float4*)(Wd + c4);
    float4 w1 = *(const float4*)(Wd + INC + c4);
    float4 bb = *(const float4*)(bd + c4);
    float4 o;
    o.x = zb0 * w0.x + zb1 * w1.x + bb.x;
    o.y = zb0 * w0.y + zb1 * w1.y + bb.y;
    o.z = zb0 * w0.z + zb1 * w1.z + bb.z;
    o.w = zb0 * w0.w + zb1 * w1.w + bb.w;
    *(float4*)(out + (size_t)row * INC + c4) = o;
}

// ---------------- launch ----------------
static inline size_t align256(size_t x) { return (x + 255) & ~(size_t)255; }

extern "C" void kernel_launch(void* const* d_in, const int* in_sizes, int n_in,
                              void* d_out, int out_size, void* d_ws, size_t ws_size,
                              hipStream_t stream) {
    const float* x  = (const float*)d_in[0];
    const int*   ei = (const int*)d_in[1];     // [2, E] int32
    const float* W1 = (const float*)d_in[2];
    const float* b1 = (const float*)d_in[3];
    const float* g1 = (const float*)d_in[4];
    const float* be1 = (const float*)d_in[5];
    const float* W2 = (const float*)d_in[6];
    const float* b2 = (const float*)d_in[7];
    const float* g2 = (const float*)d_in[8];
    const float* be2 = (const float*)d_in[9];
    const float* Wd = (const float*)d_in[10];
    const float* bd = (const float*)d_in[11];
    float* out = (float*)d_out;

    const int* src = ei;
    const int* dst = ei + NE;

    char* ws = (char*)d_ws;
    size_t off = 0;
    int* gtail = (int*)(ws + off);      off = align256(off + NBUCK * 4);
    float* sums1 = (float*)(ws + off);  off = align256(off + 128 * 4);
    float* sums2 = (float*)(ws + off);  off = align256(off + 32 * 4);
    size_t zero_bytes = off;
    int* cnt = (int*)(ws + off);        off = align256(off + NN * 4);
    int* rowptr = (int*)(ws + off);     off = align256(off + (NN + 1) * 4);
    float* dinv = (float*)(ws + off);   off = align256(off + NN * 4);
    int* btot = (int*)(ws + off);       off = align256(off + NBLK * 4);
    int* boff = (int*)(ws + off);       off = align256(off + NBLK * 4);
    unsigned short* Wtb = (unsigned short*)(ws + off); off = align256(off + (size_t)HID * INC * 2);
    unsigned int* pbuf = (unsigned int*)(ws + off); off = align256(off + (size_t)NBUCK * BCAP * 4 + 4096);
    int* e_src = (int*)(ws + off);      off = align256(off + (size_t)NE * 4 + 64);
    unsigned short* xw1h = (unsigned short*)(ws + off); off = align256(off + (size_t)NN * HID * 2);
    float* h1h = (float*)(ws + off);    off = align256(off + (size_t)NN * HID * 4);
    float* xw2 = (float*)(ws + off);    off = align256(off + (size_t)NN * 2 * 4);
    float* z2 = (float*)(ws + off);     off = align256(off + (size_t)NN * 2 * 4);
    (void)ws_size; (void)in_sizes; (void)n_in; (void)out_size;

    hipMemsetAsync(d_ws, 0, zero_bytes, stream);

    bin_kernel<<<BIN_GRID, 256, 0, stream>>>(src, dst, gtail, pbuf);
    hist2_kernel<<<NBUCK, 256, 0, stream>>>(pbuf, gtail, cnt);
    scan_btot_kernel<<<NBLK, 256, 0, stream>>>(cnt, btot);
    scan_boff_kernel<<<1, 128, 0, stream>>>(btot, boff);
    scan_rowptr_kernel<<<NBLK, 256, 0, stream>>>(cnt, boff, rowptr, dinv);
    scatter2_kernel<<<NBUCK, 256, 0, stream>>>(pbuf, gtail, rowptr, e_src);
    wprep_kernel<<<64, 256, 0, stream>>>(W1, Wtb);
    gemm1_kernel<<<NN / G1_ROWS, 256, 0, stream>>>(x, Wtb, dinv, xw1h);
    agg1_kernel<<<2048, 256, 0, stream>>>(xw1h, rowptr, e_src, dinv, b1, h1h, sums1);
    gemm2_kernel<<<(NN + 3) / 4, 256, 0, stream>>>(h1h, sums1, g1, be1, W2, dinv, xw2);
    agg2_kernel<<<NN * 8 / 256, 256, 0, stream>>>(xw2, rowptr, e_src, dinv, b2, z2, sums2);
    decoder_kernel<<<(NN * HID) / 256, 256, 0, stream>>>(z2, sums2, g2, be2, Wd, bd, out);
}

// Round 15
// 308.526 us; speedup vs baseline: 1.0043x; 1.0043x over previous
//
#include <hip/hip_runtime.h>
#include <hip/hip_bf16.h>

#define NN 100000
#define NE 3200000
#define INC 256
#define HID 64
#define OUTC 2
#define EPSV 1e-5f

#define SCAN_CHUNK 1024
#define NBLK ((NN + SCAN_CHUNK - 1) / SCAN_CHUNK)   // 98

#define NBUCK 128
#define BCAP  26000          // mean 25000, sigma ~157 -> +6.4 sigma margin
#define BIN_CHUNK 4096
#define BIN_K 16             // edges per thread (256 threads * 16 = 4096)
#define BIN_GRID ((NE + BIN_CHUNK - 1) / BIN_CHUNK)  // 782

typedef short short8 __attribute__((ext_vector_type(8)));
typedef float f32x4 __attribute__((ext_vector_type(4)));

static __device__ __forceinline__ float bf2f(unsigned short u) {
    return __uint_as_float((unsigned)u << 16);
}
static __device__ __forceinline__ unsigned short f2bf(float f) {
    __hip_bfloat16 hb = __float2bfloat16(f);   // RNE
    return *(unsigned short*)&hb;
}

// ---------------- bin: partition edges into 128 dst-range buckets ----------------
// Packed entry: (dloc<<17) | src  (src < 2^17, dloc < 800 < 2^10).
__global__ __launch_bounds__(256) void bin_kernel(const int* __restrict__ src,
                                                  const int* __restrict__ dst,
                                                  int* __restrict__ gtail,
                                                  unsigned int* __restrict__ pbuf) {
    __shared__ int bcnt[NBUCK], bbase[NBUCK];
    int t = threadIdx.x;
    if (t < NBUCK) bcnt[t] = 0;
    __syncthreads();
    int base = blockIdx.x * BIN_CHUNK;
    int s[BIN_K], d[BIN_K], sl[BIN_K], bk[BIN_K];
#pragma unroll
    for (int r = 0; r < BIN_K; r++) {
        int i = base + r * 256 + t;
        bool v = i < NE;
        s[r] = v ? src[i] : 0;
        d[r] = v ? dst[i] : 0;
        bk[r] = (int)(((unsigned)d[r] * (unsigned)NBUCK) / (unsigned)NN);
        sl[r] = v ? atomicAdd(&bcnt[bk[r]], 1) : 0;
    }
    __syncthreads();
    if (t < NBUCK) bbase[t] = bcnt[t] ? atomicAdd(&gtail[t], bcnt[t]) : 0;
    __syncthreads();
#pragma unroll
    for (int r = 0; r < BIN_K; r++) {
        int i = base + r * 256 + t;
        if (i < NE) {
            int b = bk[r];
            int nbase = (b * NN + NBUCK - 1) >> 7;
            pbuf[(size_t)b * BCAP + bbase[b] + sl[r]] =
                ((unsigned)(d[r] - nbase) << 17) | (unsigned)s[r];
        }
    }
}

// ---------------- hist2: per-bucket LDS node histogram -> cnt ----------------
__global__ __launch_bounds__(256) void hist2_kernel(const unsigned int* __restrict__ pbuf,
                                                    const int* __restrict__ gtail,
                                                    int* __restrict__ cnt) {
    __shared__ int h[800];
    int b = blockIdx.x, t = threadIdx.x;
    int nb = (b * NN + NBUCK - 1) >> 7;
    int ne_ = ((b + 1) * NN + NBUCK - 1) >> 7;
    int range = ne_ - nb;
    for (int i = t; i < range; i += 256) h[i] = 0;
    __syncthreads();
    int ecnt = gtail[b];
    const unsigned int* p = pbuf + (size_t)b * BCAP;
    for (int i = t; i < ecnt; i += 256) atomicAdd(&h[p[i] >> 17], 1);
    __syncthreads();
    for (int i = t; i < range; i += 256) cnt[nb + i] = h[i];
}

// ---------------- scan step 1: per-chunk totals ----------------
__global__ void scan_btot_kernel(const int* __restrict__ cnt, int* __restrict__ btot) {
    __shared__ int red[4];
    int b = blockIdx.x, t = threadIdx.x;
    int base = b * SCAN_CHUNK;
    int v = 0;
    for (int j = t; j < SCAN_CHUNK; j += 256) {
        int idx = base + j;
        v += (idx < NN) ? cnt[idx] : 0;
    }
    for (int o = 32; o; o >>= 1) v += __shfl_xor(v, o);
    int wave = t >> 6, lane = t & 63;
    if (lane == 0) red[wave] = v;
    __syncthreads();
    if (t == 0) btot[b] = red[0] + red[1] + red[2] + red[3];
}

// ---------------- scan step 2: exclusive scan of chunk totals ----------------
__global__ void scan_boff_kernel(const int* __restrict__ btot, int* __restrict__ boff) {
    __shared__ int wtot[2];
    int t = threadIdx.x;           // 128 threads
    int lane = t & 63, wave = t >> 6;
    int v = (t < NBLK) ? btot[t] : 0;
    int s = v;
    for (int o = 1; o < 64; o <<= 1) {
        int u = __shfl_up(s, o);
        if (lane >= o) s += u;
    }
    if (lane == 63) wtot[wave] = s;
    __syncthreads();
    int add = (wave == 1) ? wtot[0] : 0;
    if (t < NBLK) boff[t] = s - v + add;   // exclusive prefix
}

// ---------------- scan step 3: full rowptr + dinv ----------------
__global__ void scan_rowptr_kernel(const int* __restrict__ cnt, const int* __restrict__ boff,
                                   int* __restrict__ rowptr, float* __restrict__ dinv) {
    __shared__ int wsum[4];
    int b = blockIdx.x, t = threadIdx.x;
    int lane = t & 63, wave = t >> 6;
    int idx = b * SCAN_CHUNK + t * 4;
    int c0 = (idx + 0 < NN) ? cnt[idx + 0] : 0;
    int c1 = (idx + 1 < NN) ? cnt[idx + 1] : 0;
    int c2 = (idx + 2 < NN) ? cnt[idx + 2] : 0;
    int c3 = (idx + 3 < NN) ? cnt[idx + 3] : 0;
    int local = c0 + c1 + c2 + c3;
    int s = local;
    for (int o = 1; o < 64; o <<= 1) {
        int u = __shfl_up(s, o);
        if (lane >= o) s += u;
    }
    if (lane == 63) wsum[wave] = s;
    __syncthreads();
    if (t == 0) {
        int run = 0;
        for (int w = 0; w < 4; w++) { int x = wsum[w]; wsum[w] = run; run += x; }
    }
    __syncthreads();
    int start = boff[b] + wsum[wave] + (s - local);
    if (idx + 0 < NN) { rowptr[idx + 0] = start;                dinv[idx + 0] = rsqrtf((float)(c0 + 1)); }
    if (idx + 1 < NN) { rowptr[idx + 1] = start + c0;           dinv[idx + 1] = rsqrtf((float)(c1 + 1)); }
    if (idx + 2 < NN) { rowptr[idx + 2] = start + c0 + c1;      dinv[idx + 2] = rsqrtf((float)(c2 + 1)); }
    if (idx + 3 < NN) { rowptr[idx + 3] = start + c0 + c1 + c2; dinv[idx + 3] = rsqrtf((float)(c3 + 1)); }
    if (b == 0 && t == 0) rowptr[NN] = NE;
}

// ---------------- scatter2: per-bucket CSR fill (rowptr staged in LDS) ----------------
__global__ __launch_bounds__(256) void scatter2_kernel(const unsigned int* __restrict__ pbuf,
                                                       const int* __restrict__ gtail,
                                                       const int* __restrict__ rowptr,
                                                       int* __restrict__ e_src) {
    __shared__ int rp[800], fill[800];
    int b = blockIdx.x, t = threadIdx.x;
    int nb = (b * NN + NBUCK - 1) >> 7;
    int ne_ = ((b + 1) * NN + NBUCK - 1) >> 7;
    int range = ne_ - nb;
    for (int i = t; i < range; i += 256) {
        rp[i] = rowptr[nb + i];
        fill[i] = 0;
    }
    __syncthreads();
    int ecnt = gtail[b];
    const unsigned int* p = pbuf + (size_t)b * BCAP;
    for (int i = t; i < ecnt; i += 256) {
        unsigned int k = p[i];
        int loc = k >> 17;
        int pos = rp[loc] + atomicAdd(&fill[loc], 1);
        e_src[pos] = (int)(k & 0x1FFFFu);
    }
}

// ---------------- wprep: W1 [256][64] fp32 -> Wtb [64][256] bf16 (transposed) ----------------
__global__ __launch_bounds__(256) void wprep_kernel(const float* __restrict__ W1,
                                                    unsigned short* __restrict__ Wtb) {
    int t = blockIdx.x * 256 + threadIdx.x;    // 16384 threads
    int c = t & 63;
    int k = t >> 6;
    Wtb[c * 256 + k] = f2bf(W1[k * 64 + c]);
}

// ---------------- GEMM1 (MFMA): xw1[N][64] = bf16( dinv .* (x @ W1) ) ----------------
// R13-style staging (x + W in LDS); output single row-major [N][64] (128B rows).
#define G1_ROWS 32
#define LDP 264
__global__ __launch_bounds__(256) void gemm1_kernel(const float* __restrict__ x,
                                                    const unsigned short* __restrict__ Wtb,
                                                    const float* __restrict__ dinv,
                                                    unsigned short* __restrict__ xw1) {
    __shared__ unsigned short xt[G1_ROWS * LDP];   // 16896 B
    __shared__ unsigned short wt[HID * LDP];       // 33792 B
    int t = threadIdx.x;
    size_t base = (size_t)blockIdx.x * G1_ROWS;

    const float4* xg = (const float4*)(x + base * INC);
#pragma unroll
    for (int ii = 0; ii < 8; ii++) {
        int idx4 = ii * 256 + t;
        float4 v = xg[idx4];
        int f = idx4 * 4;
        int row = f >> 8, k = f & 255;
        ushort4 u;
        u.x = f2bf(v.x); u.y = f2bf(v.y); u.z = f2bf(v.z); u.w = f2bf(v.w);
        *(ushort4*)(xt + row * LDP + k) = u;
    }
    const int4* wsrc = (const int4*)Wtb;
#pragma unroll
    for (int ii = 0; ii < 8; ii++) {
        int idx4 = ii * 256 + t;
        int4 v = wsrc[idx4];
        int e16 = idx4 * 8;
        int c = e16 >> 8, k = e16 & 255;
        *(int4*)(wt + c * LDP + k) = v;
    }
    __syncthreads();

    int lane = t & 63;
    int wave = t >> 6;
    int l15 = lane & 15;
    int hi = lane >> 4;
    int rgrp = wave & 1;          // row group: 16 rows
    int cgrp = wave >> 1;         // channel half: 32 channels
    const unsigned short* ap = xt + (rgrp * 16 + l15) * LDP;
    const unsigned short* bp0 = wt + (cgrp * 32 + l15) * LDP;
    const unsigned short* bp1 = bp0 + 16 * LDP;
    f32x4 acc0 = {0.f, 0.f, 0.f, 0.f};
    f32x4 acc1 = {0.f, 0.f, 0.f, 0.f};
#pragma unroll
    for (int kk = 0; kk < 8; kk++) {
        int ko = kk * 32 + hi * 8;
        short8 a  = *(const short8*)(ap + ko);
        short8 b0 = *(const short8*)(bp0 + ko);
        short8 b1 = *(const short8*)(bp1 + ko);
        acc0 = __builtin_amdgcn_mfma_f32_16x16x32_bf16(a, b0, acc0, 0, 0, 0);
        acc1 = __builtin_amdgcn_mfma_f32_16x16x32_bf16(a, b1, acc1, 0, 0, 0);
    }
    // D: col = lane&15, row = (lane>>4)*4 + i
#pragma unroll
    for (int i = 0; i < 4; i++) {
        int grow = (int)base + rgrp * 16 + hi * 4 + i;
        float dv = dinv[grow];
        unsigned short* ph = xw1 + (size_t)grow * HID + cgrp * 32;
        ph[l15]      = f2bf(acc0[i] * dv);
        ph[l15 + 16] = f2bf(acc1[i] * dv);
    }
}

// ---------------- agg1: 16-lane group per node, ONE full-row visit per edge ----------------
// Group of 16 lanes gathers a whole 128B xw1 row per edge (ushort4/lane = 4 ch)
// -> 3.2M visits total (half of R11/R13). Register accumulation, unroll x4.
// h1 written row-major [N][64] (256B per node from the group).
__global__ __launch_bounds__(256) void agg1_kernel(const unsigned short* __restrict__ xw1,
                                                   const int* __restrict__ rowptr,
                                                   const int* __restrict__ e_src,
                                                   const float* __restrict__ dinv,
                                                   const float* __restrict__ b1,
                                                   float* __restrict__ h1,
                                                   float* __restrict__ sums1) {
    __shared__ float lsum[4][64], lsq[4][64];
    int t = threadIdx.x;
    int lane = t & 63;
    int wave = t >> 6;
    int grp = lane >> 4;          // 4 node-groups per wave
    int cl = lane & 15;           // ushort4 slot: channels cl*4 .. cl*4+3
    const ushort4* plane = (const ushort4*)xw1;   // row = 16 ushort4
    float bb0 = b1[cl * 4 + 0];
    float bb1 = b1[cl * 4 + 1];
    float bb2 = b1[cl * 4 + 2];
    float bb3 = b1[cl * 4 + 3];
    int gid = (blockIdx.x * 4 + wave) * 4 + grp;   // 0..32767
    float ss0 = 0.f, ss1 = 0.f, ss2 = 0.f, ss3 = 0.f;
    float sq0 = 0.f, sq1 = 0.f, sq2 = 0.f, sq3 = 0.f;
    for (int d = gid; d < NN; d += 32768) {
        int beg = rowptr[d], end = rowptr[d + 1];
        float a0 = 0.f, a1 = 0.f, a2 = 0.f, a3 = 0.f;
        int e = beg;
        for (; e + 3 < end; e += 4) {          // 4 independent 128B row-gathers
            int s0 = e_src[e], s1 = e_src[e + 1], s2 = e_src[e + 2], s3 = e_src[e + 3];
            ushort4 u0 = plane[(size_t)s0 * 16 + cl];
            ushort4 u1 = plane[(size_t)s1 * 16 + cl];
            ushort4 u2 = plane[(size_t)s2 * 16 + cl];
            ushort4 u3 = plane[(size_t)s3 * 16 + cl];
            a0 += bf2f(u0.x) + bf2f(u1.x) + bf2f(u2.x) + bf2f(u3.x);
            a1 += bf2f(u0.y) + bf2f(u1.y) + bf2f(u2.y) + bf2f(u3.y);
            a2 += bf2f(u0.z) + bf2f(u1.z) + bf2f(u2.z) + bf2f(u3.z);
            a3 += bf2f(u0.w) + bf2f(u1.w) + bf2f(u2.w) + bf2f(u3.w);
        }
        for (; e < end; e++) {
            int s = e_src[e];
            ushort4 u = plane[(size_t)s * 16 + cl];
            a0 += bf2f(u.x); a1 += bf2f(u.y); a2 += bf2f(u.z); a3 += bf2f(u.w);
        }
        ushort4 us = plane[(size_t)d * 16 + cl];    // self-loop
        a0 += bf2f(us.x); a1 += bf2f(us.y); a2 += bf2f(us.z); a3 += bf2f(us.w);
        float dv = dinv[d];
        float h0 = a0 * dv + bb0;
        float h1v = a1 * dv + bb1;
        float h2 = a2 * dv + bb2;
        float h3 = a3 * dv + bb3;
        f32x4 hv = {h0, h1v, h2, h3};
        ((f32x4*)(h1 + (size_t)d * HID))[cl] = hv;
        ss0 += h0; sq0 += h0 * h0;
        ss1 += h1v; sq1 += h1v * h1v;
        ss2 += h2; sq2 += h2 * h2;
        ss3 += h3; sq3 += h3 * h3;
    }
    // stats: reduce across the 4 groups (stride-16 lanes share cl)
#pragma unroll
    for (int o = 16; o < 64; o <<= 1) {
        ss0 += __shfl_xor(ss0, o); sq0 += __shfl_xor(sq0, o);
        ss1 += __shfl_xor(ss1, o); sq1 += __shfl_xor(sq1, o);
        ss2 += __shfl_xor(ss2, o); sq2 += __shfl_xor(sq2, o);
        ss3 += __shfl_xor(ss3, o); sq3 += __shfl_xor(sq3, o);
    }
    if (grp == 0) {
        lsum[wave][cl * 4 + 0] = ss0; lsq[wave][cl * 4 + 0] = sq0;
        lsum[wave][cl * 4 + 1] = ss1; lsq[wave][cl * 4 + 1] = sq1;
        lsum[wave][cl * 4 + 2] = ss2; lsq[wave][cl * 4 + 2] = sq2;
        lsum[wave][cl * 4 + 3] = ss3; lsq[wave][cl * 4 + 3] = sq3;
    }
    __syncthreads();
    if (t < 64) {
        float S = lsum[0][t] + lsum[1][t] + lsum[2][t] + lsum[3][t];
        float Q = lsq[0][t] + lsq[1][t] + lsq[2][t] + lsq[3][t];
        atomicAdd(&sums1[t], S);
        atomicAdd(&sums1[64 + t], Q);
    }
}

// ---------------- gemm2: xw2' = dinv .* (relu(BN1(h1)) @ W2) ----------------
__global__ __launch_bounds__(256) void gemm2_kernel(const float* __restrict__ h1,
                                                    const float* __restrict__ sums1,
                                                    const float* __restrict__ g1,
                                                    const float* __restrict__ be1,
                                                    const float* __restrict__ W2,
                                                    const float* __restrict__ dinv,
                                                    float* __restrict__ xw2) {
    int lane = threadIdx.x & 63;
    int row = blockIdx.x * 4 + (threadIdx.x >> 6);
    if (row >= NN) return;
    int c = lane;
    const float invn = 1.0f / (float)NN;
    float mu = sums1[c] * invn;
    float var = sums1[64 + c] * invn - mu * mu;
    float sc = g1[c] * rsqrtf(var + EPSV);
    float sh = be1[c] - mu * sc;
    float hv = h1[(size_t)row * HID + c] * sc + sh;
    hv = fmaxf(hv, 0.f);
    float p0 = hv * W2[c * 2 + 0];
    float p1 = hv * W2[c * 2 + 1];
    for (int o = 32; o; o >>= 1) {
        p0 += __shfl_xor(p0, o);
        p1 += __shfl_xor(p1, o);
    }
    if (lane == 0) {
        float dv = dinv[row];
        xw2[(size_t)row * 2 + 0] = p0 * dv;
        xw2[(size_t)row * 2 + 1] = p1 * dv;
    }
}

// ---------------- agg2: 8-lane group per node, banked stats ----------------
__global__ __launch_bounds__(256) void agg2_kernel(const float* __restrict__ xw2,
                                                   const int* __restrict__ rowptr,
                                                   const int* __restrict__ e_src,
                                                   const float* __restrict__ dinv,
                                                   const float* __restrict__ b2,
                                                   float* __restrict__ z2,
                                                   float* __restrict__ sums2) {
    __shared__ float red[4][4];
    int t = threadIdx.x;
    int lane = t & 63;
    int wave = t >> 6;
    int gl = lane & 7;                       // lane within node-group
    int d = blockIdx.x * 32 + (t >> 3);      // grid sized so d < NN always
    int beg = rowptr[d], end = rowptr[d + 1];
    float a0 = 0.f, a1 = 0.f;
    int e = beg + gl;
    for (; e + 24 < end; e += 32) {          // 4 independent gathers in flight
        int s0 = e_src[e], s1 = e_src[e + 8], s2 = e_src[e + 16], s3 = e_src[e + 24];
        float2 v0 = *(const float2*)(xw2 + (size_t)s0 * 2);
        float2 v1 = *(const float2*)(xw2 + (size_t)s1 * 2);
        float2 v2 = *(const float2*)(xw2 + (size_t)s2 * 2);
        float2 v3 = *(const float2*)(xw2 + (size_t)s3 * 2);
        a0 += v0.x + v1.x + v2.x + v3.x;
        a1 += v0.y + v1.y + v2.y + v3.y;
    }
    for (; e < end; e += 8) {
        int s = e_src[e];
        float2 v = *(const float2*)(xw2 + (size_t)s * 2);
        a0 += v.x;
        a1 += v.y;
    }
    if (gl == 0) {                           // self-loop
        float2 sf = *(const float2*)(xw2 + (size_t)d * 2);
        a0 += sf.x;
        a1 += sf.y;
    }
    a0 += __shfl_xor(a0, 1); a1 += __shfl_xor(a1, 1);
    a0 += __shfl_xor(a0, 2); a1 += __shfl_xor(a1, 2);
    a0 += __shfl_xor(a0, 4); a1 += __shfl_xor(a1, 4);
    float dv = dinv[d];
    float z0 = a0 * dv + b2[0];
    float z1 = a1 * dv + b2[1];
    if (gl == 0) *(float2*)(z2 + (size_t)d * 2) = make_float2(z0, z1);
    float s0 = (gl == 0) ? z0 : 0.f;
    float s1 = (gl == 0) ? z1 : 0.f;
    float q0 = (gl == 0) ? z0 * z0 : 0.f;
    float q1 = (gl == 0) ? z1 * z1 : 0.f;
    for (int o = 8; o < 64; o <<= 1) {
        s0 += __shfl_xor(s0, o); s1 += __shfl_xor(s1, o);
        q0 += __shfl_xor(q0, o); q1 += __shfl_xor(q1, o);
    }
    if (lane == 0) { red[wave][0] = s0; red[wave][1] = s1; red[wave][2] = q0; red[wave][3] = q1; }
    __syncthreads();
    if (t < 4) {
        float v = red[0][t] + red[1][t] + red[2][t] + red[3][t];
        atomicAdd(&sums2[(blockIdx.x & 7) * 4 + t], v);   // 8 banks
    }
}

// ---------------- decoder: out = BN2(z2) @ Wd + bd (sums2 banked [8][4]) ----------------
__global__ __launch_bounds__(256) void decoder_kernel(const float* __restrict__ z2,
                                                      const float* __restrict__ sums2,
                                                      const float* __restrict__ g2,
                                                      const float* __restrict__ be2,
                                                      const float* __restrict__ Wd,
                                                      const float* __restrict__ bd,
                                                      float* __restrict__ out) {
    int g = blockIdx.x * 256 + threadIdx.x;
    int row = g >> 6;
    int c4 = (g & 63) * 4;
    float t0 = 0.f, t1 = 0.f, t2 = 0.f, t3 = 0.f;
#pragma unroll
    for (int bk = 0; bk < 8; bk++) {
        t0 += sums2[bk * 4 + 0]; t1 += sums2[bk * 4 + 1];
        t2 += sums2[bk * 4 + 2]; t3 += sums2[bk * 4 + 3];
    }
    const float invn = 1.0f / (float)NN;
    float mu0 = t0 * invn, mu1 = t1 * invn;
    float v0 = t2 * invn - mu0 * mu0;
    float v1 = t3 * invn - mu1 * mu1;
    float sc0 = g2[0] * rsqrtf(v0 + EPSV), sh0 = be2[0] - mu0 * sc0;
    float sc1 = g2[1] * rsqrtf(v1 + EPSV), sh1 = be2[1] - mu1 * sc1;
    float zb0 = z2[(size_t)row * 2 + 0] * sc0 + sh0;
    float zb1 = z2[(size_t)row * 2 + 1] * sc1 + sh1;
    float4 w0 = *(const float4*)(Wd + c4);
    float4 w1 = *(const float4*)(Wd + INC + c4);
    float4 bb = *(const float4*)(bd + c4);
    float4 o;
    o.x = zb0 * w0.x + zb1 * w1.x + bb.x;
    o.y = zb0 * w0.y + zb1 * w1.y + bb.y;
    o.z = zb0 * w0.z + zb1 * w1.z + bb.z;
    o.w = zb0 * w0.w + zb1 * w1.w + bb.w;
    *(float4*)(out + (size_t)row * INC + c4) = o;
}

// ---------------- launch ----------------
static inline size_t align256(size_t x) { return (x + 255) & ~(size_t)255; }

extern "C" void kernel_launch(void* const* d_in, const int* in_sizes, int n_in,
                              void* d_out, int out_size, void* d_ws, size_t ws_size,
                              hipStream_t stream) {
    const float* x  = (const float*)d_in[0];
    const int*   ei = (const int*)d_in[1];     // [2, E] int32
    const float* W1 = (const float*)d_in[2];
    const float* b1 = (const float*)d_in[3];
    const float* g1 = (const float*)d_in[4];
    const float* be1 = (const float*)d_in[5];
    const float* W2 = (const float*)d_in[6];
    const float* b2 = (const float*)d_in[7];
    const float* g2 = (const float*)d_in[8];
    const float* be2 = (const float*)d_in[9];
    const float* Wd = (const float*)d_in[10];
    const float* bd = (const float*)d_in[11];
    float* out = (float*)d_out;

    const int* src = ei;
    const int* dst = ei + NE;

    char* ws = (char*)d_ws;
    size_t off = 0;
    int* gtail = (int*)(ws + off);      off = align256(off + NBUCK * 4);
    float* sums1 = (float*)(ws + off);  off = align256(off + 128 * 4);
    float* sums2 = (float*)(ws + off);  off = align256(off + 32 * 4);
    size_t zero_bytes = off;
    int* cnt = (int*)(ws + off);        off = align256(off + NN * 4);
    int* rowptr = (int*)(ws + off);     off = align256(off + (NN + 1) * 4);
    float* dinv = (float*)(ws + off);   off = align256(off + NN * 4);
    int* btot = (int*)(ws + off);       off = align256(off + NBLK * 4);
    int* boff = (int*)(ws + off);       off = align256(off + NBLK * 4);
    unsigned short* Wtb = (unsigned short*)(ws + off); off = align256(off + (size_t)HID * INC * 2);
    unsigned int* pbuf = (unsigned int*)(ws + off); off = align256(off + (size_t)NBUCK * BCAP * 4 + 4096);
    int* e_src = (int*)(ws + off);      off = align256(off + (size_t)NE * 4 + 64);
    unsigned short* xw1 = (unsigned short*)(ws + off); off = align256(off + (size_t)NN * HID * 2);
    float* h1 = (float*)(ws + off);     off = align256(off + (size_t)NN * HID * 4);
    float* xw2 = (float*)(ws + off);    off = align256(off + (size_t)NN * 2 * 4);
    float* z2 = (float*)(ws + off);     off = align256(off + (size_t)NN * 2 * 4);
    (void)ws_size; (void)in_sizes; (void)n_in; (void)out_size;

    hipMemsetAsync(d_ws, 0, zero_bytes, stream);

    bin_kernel<<<BIN_GRID, 256, 0, stream>>>(src, dst, gtail, pbuf);
    hist2_kernel<<<NBUCK, 256, 0, stream>>>(pbuf, gtail, cnt);
    scan_btot_kernel<<<NBLK, 256, 0, stream>>>(cnt, btot);
    scan_boff_kernel<<<1, 128, 0, stream>>>(btot, boff);
    scan_rowptr_kernel<<<NBLK, 256, 0, stream>>>(cnt, boff, rowptr, dinv);
    scatter2_kernel<<<NBUCK, 256, 0, stream>>>(pbuf, gtail, rowptr, e_src);
    wprep_kernel<<<64, 256, 0, stream>>>(W1, Wtb);
    gemm1_kernel<<<NN / G1_ROWS, 256, 0, stream>>>(x, Wtb, dinv, xw1);
    agg1_kernel<<<2048, 256, 0, stream>>>(xw1, rowptr, e_src, dinv, b1, h1, sums1);
    gemm2_kernel<<<(NN + 3) / 4, 256, 0, stream>>>(h1, sums1, g1, be1, W2, dinv, xw2);
    agg2_kernel<<<NN * 8 / 256, 256, 0, stream>>>(xw2, rowptr, e_src, dinv, b2, z2, sums2);
    decoder_kernel<<<(NN * HID) / 256, 256, 0, stream>>>(z2, sums2, g2, be2, Wd, bd, out);
}

// Round 16
// 292.519 us; speedup vs baseline: 1.0592x; 1.0547x over previous
//
#include <hip/hip_runtime.h>
#include <hip/hip_bf16.h>

#define NN 100000
#define NE 3200000
#define INC 256
#define HID 64
#define OUTC 2
#define EPSV 1e-5f

#define NBUCK 128
#define BCAP  26000          // mean 25000, sigma ~157 -> +6.4 sigma margin
#define BIN_CHUNK 4096
#define BIN_K 16             // edges per thread (256 threads * 16 = 4096)
#define BIN_GRID ((NE + BIN_CHUNK - 1) / BIN_CHUNK)  // 782

#define NQUART 25000         // dst quarter (2 ch-halves x 4 dst-quarters = 8 cohorts)

typedef short short8 __attribute__((ext_vector_type(8)));
typedef float f32x4 __attribute__((ext_vector_type(4)));

static __device__ __forceinline__ float bf2f(unsigned short u) {
    return __uint_as_float((unsigned)u << 16);
}
static __device__ __forceinline__ unsigned short f2bf(float f) {
    __hip_bfloat16 hb = __float2bfloat16(f);   // RNE
    return *(unsigned short*)&hb;
}

// ---------------- bin: partition edges into 128 dst-range buckets ----------------
// Packed entry: (dloc<<17) | src  (src < 2^17, dloc < 800 < 2^10).
__global__ __launch_bounds__(256) void bin_kernel(const int* __restrict__ src,
                                                  const int* __restrict__ dst,
                                                  int* __restrict__ gtail,
                                                  unsigned int* __restrict__ pbuf) {
    __shared__ int bcnt[NBUCK], bbase[NBUCK];
    int t = threadIdx.x;
    if (t < NBUCK) bcnt[t] = 0;
    __syncthreads();
    int base = blockIdx.x * BIN_CHUNK;
    int s[BIN_K], d[BIN_K], sl[BIN_K], bk[BIN_K];
#pragma unroll
    for (int r = 0; r < BIN_K; r++) {
        int i = base + r * 256 + t;
        bool v = i < NE;
        s[r] = v ? src[i] : 0;
        d[r] = v ? dst[i] : 0;
        bk[r] = (int)(((unsigned)d[r] * (unsigned)NBUCK) / (unsigned)NN);
        sl[r] = v ? atomicAdd(&bcnt[bk[r]], 1) : 0;
    }
    __syncthreads();
    if (t < NBUCK) bbase[t] = bcnt[t] ? atomicAdd(&gtail[t], bcnt[t]) : 0;
    __syncthreads();
#pragma unroll
    for (int r = 0; r < BIN_K; r++) {
        int i = base + r * 256 + t;
        if (i < NE) {
            int b = bk[r];
            int nbase = (b * NN + NBUCK - 1) >> 7;
            pbuf[(size_t)b * BCAP + bbase[b] + sl[r]] =
                ((unsigned)(d[r] - nbase) << 17) | (unsigned)s[r];
        }
    }
}

// ---------------- bscan: exclusive scan of 128 bucket totals -> bbase ----------------
__global__ void bscan_kernel(const int* __restrict__ gtail, int* __restrict__ bbase) {
    __shared__ int wtot[2];
    int t = threadIdx.x;           // 128 threads
    int lane = t & 63, wave = t >> 6;
    int v = gtail[t];
    int s = v;
    for (int o = 1; o < 64; o <<= 1) {
        int u = __shfl_up(s, o);
        if (lane >= o) s += u;
    }
    if (lane == 63) wtot[wave] = s;
    __syncthreads();
    int add = (wave == 1) ? wtot[0] : 0;
    bbase[t] = s - v + add;        // exclusive prefix
}

// ---------------- build: per-bucket {histogram -> scan -> rowptr+dinv -> scatter} ----------------
// Fuses hist2 + scan_rowptr + scatter2. rowptr stays in LDS for the scatter.
__global__ __launch_bounds__(256) void build_kernel(const unsigned int* __restrict__ pbuf,
                                                    const int* __restrict__ gtail,
                                                    const int* __restrict__ bbase,
                                                    int* __restrict__ rowptr,
                                                    float* __restrict__ dinv,
                                                    int* __restrict__ e_src) {
    __shared__ int h[800], rp[800];
    __shared__ int wsum[4];
    int b = blockIdx.x, t = threadIdx.x;
    int nb = (b * NN + NBUCK - 1) >> 7;
    int ne_ = ((b + 1) * NN + NBUCK - 1) >> 7;
    int range = ne_ - nb;
    for (int i = t; i < range; i += 256) h[i] = 0;
    __syncthreads();
    int ecnt = gtail[b];
    const unsigned int* p = pbuf + (size_t)b * BCAP;
    for (int i = t; i < ecnt; i += 256) atomicAdd(&h[p[i] >> 17], 1);
    __syncthreads();
    // block-wide exclusive scan of h[0..range): thread t owns 4 slots
    int idx = t * 4;
    int c0 = (idx + 0 < range) ? h[idx + 0] : 0;
    int c1 = (idx + 1 < range) ? h[idx + 1] : 0;
    int c2 = (idx + 2 < range) ? h[idx + 2] : 0;
    int c3 = (idx + 3 < range) ? h[idx + 3] : 0;
    int local = c0 + c1 + c2 + c3;
    int lane = t & 63, wave = t >> 6;
    int s = local;
    for (int o = 1; o < 64; o <<= 1) {
        int u = __shfl_up(s, o);
        if (lane >= o) s += u;
    }
    if (lane == 63) wsum[wave] = s;
    __syncthreads();
    if (t == 0) {
        int run = 0;
        for (int w = 0; w < 4; w++) { int x = wsum[w]; wsum[w] = run; run += x; }
    }
    __syncthreads();
    int start = wsum[wave] + (s - local);
    int gb = bbase[b];
    if (idx + 0 < range) { rp[idx + 0] = start;                rowptr[nb + idx + 0] = gb + start;                dinv[nb + idx + 0] = rsqrtf((float)(c0 + 1)); }
    if (idx + 1 < range) { rp[idx + 1] = start + c0;           rowptr[nb + idx + 1] = gb + start + c0;           dinv[nb + idx + 1] = rsqrtf((float)(c1 + 1)); }
    if (idx + 2 < range) { rp[idx + 2] = start + c0 + c1;      rowptr[nb + idx + 2] = gb + start + c0 + c1;      dinv[nb + idx + 2] = rsqrtf((float)(c2 + 1)); }
    if (idx + 3 < range) { rp[idx + 3] = start + c0 + c1 + c2; rowptr[nb + idx + 3] = gb + start + c0 + c1 + c2; dinv[nb + idx + 3] = rsqrtf((float)(c3 + 1)); }
    if (b == NBUCK - 1 && t == 0) rowptr[NN] = NE;
    __syncthreads();
    // reuse h as fill counters
    for (int i = t; i < range; i += 256) h[i] = 0;
    __syncthreads();
    for (int i = t; i < ecnt; i += 256) {
        unsigned int k = p[i];
        int loc = k >> 17;
        int pos = gb + rp[loc] + atomicAdd(&h[loc], 1);
        e_src[pos] = (int)(k & 0x1FFFFu);
    }
}

// ---------------- wprep: W1 [256][64] fp32 -> Wtb [64][256] bf16 (transposed) ----------------
__global__ __launch_bounds__(256) void wprep_kernel(const float* __restrict__ W1,
                                                    unsigned short* __restrict__ Wtb) {
    int t = blockIdx.x * 256 + threadIdx.x;    // 16384 threads
    int c = t & 63;
    int k = t >> 6;
    Wtb[c * 256 + k] = f2bf(W1[k * 64 + c]);
}

// ---------------- GEMM1 (MFMA): xw1h[half][N][32] = bf16( dinv .* (x @ W1) ) ----------------
// LDS-staged x + W (R13 config, best measured). Half-plane output (64B rows).
#define G1_ROWS 32
#define LDP 264
__global__ __launch_bounds__(256) void gemm1_kernel(const float* __restrict__ x,
                                                    const unsigned short* __restrict__ Wtb,
                                                    const float* __restrict__ dinv,
                                                    unsigned short* __restrict__ xw1h) {
    __shared__ unsigned short xt[G1_ROWS * LDP];   // 16896 B
    __shared__ unsigned short wt[HID * LDP];       // 33792 B
    int t = threadIdx.x;
    size_t base = (size_t)blockIdx.x * G1_ROWS;

    const float4* xg = (const float4*)(x + base * INC);
#pragma unroll
    for (int ii = 0; ii < 8; ii++) {
        int idx4 = ii * 256 + t;
        float4 v = xg[idx4];
        int f = idx4 * 4;
        int row = f >> 8, k = f & 255;
        ushort4 u;
        u.x = f2bf(v.x); u.y = f2bf(v.y); u.z = f2bf(v.z); u.w = f2bf(v.w);
        *(ushort4*)(xt + row * LDP + k) = u;
    }
    const int4* wsrc = (const int4*)Wtb;
#pragma unroll
    for (int ii = 0; ii < 8; ii++) {
        int idx4 = ii * 256 + t;
        int4 v = wsrc[idx4];
        int e16 = idx4 * 8;
        int c = e16 >> 8, k = e16 & 255;
        *(int4*)(wt + c * LDP + k) = v;
    }
    __syncthreads();

    int lane = t & 63;
    int wave = t >> 6;
    int l15 = lane & 15;
    int hi = lane >> 4;
    int rgrp = wave & 1;          // row group: 16 rows
    int cgrp = wave >> 1;         // channel half: 32 channels
    const unsigned short* ap = xt + (rgrp * 16 + l15) * LDP;
    const unsigned short* bp0 = wt + (cgrp * 32 + l15) * LDP;
    const unsigned short* bp1 = bp0 + 16 * LDP;
    f32x4 acc0 = {0.f, 0.f, 0.f, 0.f};
    f32x4 acc1 = {0.f, 0.f, 0.f, 0.f};
#pragma unroll
    for (int kk = 0; kk < 8; kk++) {
        int ko = kk * 32 + hi * 8;
        short8 a  = *(const short8*)(ap + ko);
        short8 b0 = *(const short8*)(bp0 + ko);
        short8 b1 = *(const short8*)(bp1 + ko);
        acc0 = __builtin_amdgcn_mfma_f32_16x16x32_bf16(a, b0, acc0, 0, 0, 0);
        acc1 = __builtin_amdgcn_mfma_f32_16x16x32_bf16(a, b1, acc1, 0, 0, 0);
    }
    // D: col = lane&15, row = (lane>>4)*4 + i
    unsigned short* ph = xw1h + (size_t)cgrp * NN * 32;
#pragma unroll
    for (int i = 0; i < 4; i++) {
        int grow = (int)base + rgrp * 16 + hi * 4 + i;
        float dv = dinv[grow];
        ph[(size_t)grow * 32 + l15]      = f2bf(acc0[i] * dv);
        ph[(size_t)grow * 32 + l15 + 16] = f2bf(acc1[i] * dv);
    }
}

// ---------------- agg1: 8-lane group per node, full-line gathers (R11/R14 best config) ----------------
__global__ __launch_bounds__(256) void agg1_kernel(const unsigned short* __restrict__ xw1h,
                                                   const int* __restrict__ rowptr,
                                                   const int* __restrict__ e_src,
                                                   const float* __restrict__ dinv,
                                                   const float* __restrict__ b1,
                                                   float* __restrict__ h1h,
                                                   float* __restrict__ sums1) {
    __shared__ float lsum[4][32], lsq[4][32];
    int t = threadIdx.x;
    int lane = t & 63;
    int wave = t >> 6;
    int grp = lane >> 3;          // node group within wave (8 groups)
    int cl = lane & 7;            // ushort4 slot: channels cl*4 .. cl*4+3
    int cohort = blockIdx.x & 7;
    int h = cohort & 1;           // channel half
    int dq = cohort >> 1;         // dst quarter
    const ushort4* plane = (const ushort4*)(xw1h + (size_t)h * NN * 32);
    float* hp = h1h + (size_t)h * NN * 32;
    float bb0 = b1[h * 32 + cl * 4 + 0];
    float bb1 = b1[h * 32 + cl * 4 + 1];
    float bb2 = b1[h * 32 + cl * 4 + 2];
    float bb3 = b1[h * 32 + cl * 4 + 3];
    int gid = ((blockIdx.x >> 3) * 4 + wave) * 8 + grp;   // 0..8191 per cohort
    int dlo = dq * NQUART;
    float ss0 = 0.f, ss1 = 0.f, ss2 = 0.f, ss3 = 0.f;
    float sq0 = 0.f, sq1 = 0.f, sq2 = 0.f, sq3 = 0.f;
    for (int d = dlo + gid; d < dlo + NQUART; d += 8192) {
        int beg = rowptr[d], end = rowptr[d + 1];
        float a0 = 0.f, a1 = 0.f, a2 = 0.f, a3 = 0.f;
        int e = beg;
        for (; e + 3 < end; e += 4) {          // 4 independent 64B line-gathers
            int s0 = e_src[e], s1 = e_src[e + 1], s2 = e_src[e + 2], s3 = e_src[e + 3];
            ushort4 u0 = plane[(size_t)s0 * 8 + cl];
            ushort4 u1 = plane[(size_t)s1 * 8 + cl];
            ushort4 u2 = plane[(size_t)s2 * 8 + cl];
            ushort4 u3 = plane[(size_t)s3 * 8 + cl];
            a0 += bf2f(u0.x) + bf2f(u1.x) + bf2f(u2.x) + bf2f(u3.x);
            a1 += bf2f(u0.y) + bf2f(u1.y) + bf2f(u2.y) + bf2f(u3.y);
            a2 += bf2f(u0.z) + bf2f(u1.z) + bf2f(u2.z) + bf2f(u3.z);
            a3 += bf2f(u0.w) + bf2f(u1.w) + bf2f(u2.w) + bf2f(u3.w);
        }
        for (; e < end; e++) {
            int s = e_src[e];
            ushort4 u = plane[(size_t)s * 8 + cl];
            a0 += bf2f(u.x); a1 += bf2f(u.y); a2 += bf2f(u.z); a3 += bf2f(u.w);
        }
        ushort4 us = plane[(size_t)d * 8 + cl];    // self-loop
        a0 += bf2f(us.x); a1 += bf2f(us.y); a2 += bf2f(us.z); a3 += bf2f(us.w);
        float dv = dinv[d];
        float h0 = a0 * dv + bb0;
        float h1v = a1 * dv + bb1;
        float h2 = a2 * dv + bb2;
        float h3 = a3 * dv + bb3;
        f32x4 hv = {h0, h1v, h2, h3};
        *(f32x4*)(hp + (size_t)d * 32 + cl * 4) = hv;
        ss0 += h0; sq0 += h0 * h0;
        ss1 += h1v; sq1 += h1v * h1v;
        ss2 += h2; sq2 += h2 * h2;
        ss3 += h3; sq3 += h3 * h3;
    }
    // stats: reduce across the 8 groups (stride-8 lanes share cl)
#pragma unroll
    for (int o = 8; o < 64; o <<= 1) {
        ss0 += __shfl_xor(ss0, o); sq0 += __shfl_xor(sq0, o);
        ss1 += __shfl_xor(ss1, o); sq1 += __shfl_xor(sq1, o);
        ss2 += __shfl_xor(ss2, o); sq2 += __shfl_xor(sq2, o);
        ss3 += __shfl_xor(ss3, o); sq3 += __shfl_xor(sq3, o);
    }
    if (grp == 0) {
        lsum[wave][cl * 4 + 0] = ss0; lsq[wave][cl * 4 + 0] = sq0;
        lsum[wave][cl * 4 + 1] = ss1; lsq[wave][cl * 4 + 1] = sq1;
        lsum[wave][cl * 4 + 2] = ss2; lsq[wave][cl * 4 + 2] = sq2;
        lsum[wave][cl * 4 + 3] = ss3; lsq[wave][cl * 4 + 3] = sq3;
    }
    __syncthreads();
    if (t < 32) {
        float S = lsum[0][t] + lsum[1][t] + lsum[2][t] + lsum[3][t];
        float Q = lsq[0][t] + lsq[1][t] + lsq[2][t] + lsq[3][t];
        atomicAdd(&sums1[h * 32 + t], S);
        atomicAdd(&sums1[64 + h * 32 + t], Q);
    }
}

// ---------------- gemm2: xw2' = dinv .* (relu(BN1(h1)) @ W2) ----------------
__global__ __launch_bounds__(256) void gemm2_kernel(const float* __restrict__ h1h,
                                                    const float* __restrict__ sums1,
                                                    const float* __restrict__ g1,
                                                    const float* __restrict__ be1,
                                                    const float* __restrict__ W2,
                                                    const float* __restrict__ dinv,
                                                    float* __restrict__ xw2) {
    int lane = threadIdx.x & 63;
    int row = blockIdx.x * 4 + (threadIdx.x >> 6);
    if (row >= NN) return;
    int c = lane;
    const float invn = 1.0f / (float)NN;
    float mu = sums1[c] * invn;
    float var = sums1[64 + c] * invn - mu * mu;
    float sc = g1[c] * rsqrtf(var + EPSV);
    float sh = be1[c] - mu * sc;
    float hv = h1h[(size_t)(c >> 5) * NN * 32 + (size_t)row * 32 + (c & 31)] * sc + sh;
    hv = fmaxf(hv, 0.f);
    float p0 = hv * W2[c * 2 + 0];
    float p1 = hv * W2[c * 2 + 1];
    for (int o = 32; o; o >>= 1) {
        p0 += __shfl_xor(p0, o);
        p1 += __shfl_xor(p1, o);
    }
    if (lane == 0) {
        float dv = dinv[row];
        xw2[(size_t)row * 2 + 0] = p0 * dv;
        xw2[(size_t)row * 2 + 1] = p1 * dv;
    }
}

// ---------------- agg2: 8-lane group per node, banked stats ----------------
__global__ __launch_bounds__(256) void agg2_kernel(const float* __restrict__ xw2,
                                                   const int* __restrict__ rowptr,
                                                   const int* __restrict__ e_src,
                                                   const float* __restrict__ dinv,
                                                   const float* __restrict__ b2,
                                                   float* __restrict__ z2,
                                                   float* __restrict__ sums2) {
    __shared__ float red[4][4];
    int t = threadIdx.x;
    int lane = t & 63;
    int wave = t >> 6;
    int gl = lane & 7;                       // lane within node-group
    int d = blockIdx.x * 32 + (t >> 3);      // grid sized so d < NN always
    int beg = rowptr[d], end = rowptr[d + 1];
    float a0 = 0.f, a1 = 0.f;
    int e = beg + gl;
    for (; e + 24 < end; e += 32) {          // 4 independent gathers in flight
        int s0 = e_src[e], s1 = e_src[e + 8], s2 = e_src[e + 16], s3 = e_src[e + 24];
        float2 v0 = *(const float2*)(xw2 + (size_t)s0 * 2);
        float2 v1 = *(const float2*)(xw2 + (size_t)s1 * 2);
        float2 v2 = *(const float2*)(xw2 + (size_t)s2 * 2);
        float2 v3 = *(const float2*)(xw2 + (size_t)s3 * 2);
        a0 += v0.x + v1.x + v2.x + v3.x;
        a1 += v0.y + v1.y + v2.y + v3.y;
    }
    for (; e < end; e += 8) {
        int s = e_src[e];
        float2 v = *(const float2*)(xw2 + (size_t)s * 2);
        a0 += v.x;
        a1 += v.y;
    }
    if (gl == 0) {                           // self-loop
        float2 sf = *(const float2*)(xw2 + (size_t)d * 2);
        a0 += sf.x;
        a1 += sf.y;
    }
    a0 += __shfl_xor(a0, 1); a1 += __shfl_xor(a1, 1);
    a0 += __shfl_xor(a0, 2); a1 += __shfl_xor(a1, 2);
    a0 += __shfl_xor(a0, 4); a1 += __shfl_xor(a1, 4);
    float dv = dinv[d];
    float z0 = a0 * dv + b2[0];
    float z1 = a1 * dv + b2[1];
    if (gl == 0) *(float2*)(z2 + (size_t)d * 2) = make_float2(z0, z1);
    float s0 = (gl == 0) ? z0 : 0.f;
    float s1 = (gl == 0) ? z1 : 0.f;
    float q0 = (gl == 0) ? z0 * z0 : 0.f;
    float q1 = (gl == 0) ? z1 * z1 : 0.f;
    for (int o = 8; o < 64; o <<= 1) {
        s0 += __shfl_xor(s0, o); s1 += __shfl_xor(s1, o);
        q0 += __shfl_xor(q0, o); q1 += __shfl_xor(q1, o);
    }
    if (lane == 0) { red[wave][0] = s0; red[wave][1] = s1; red[wave][2] = q0; red[wave][3] = q1; }
    __syncthreads();
    if (t < 4) {
        float v = red[0][t] + red[1][t] + red[2][t] + red[3][t];
        atomicAdd(&sums2[(blockIdx.x & 7) * 4 + t], v);   // 8 banks
    }
}

// ---------------- decoder: out = BN2(z2) @ Wd + bd (sums2 banked [8][4]) ----------------
__global__ __launch_bounds__(256) void decoder_kernel(const float* __restrict__ z2,
                                                      const float* __restrict__ sums2,
                                                      const float* __restrict__ g2,
                                                      const float* __restrict__ be2,
                                                      const float* __restrict__ Wd,
                                                      const float* __restrict__ bd,
                                                      float* __restrict__ out) {
    int g = blockIdx.x * 256 + threadIdx.x;
    int row = g >> 6;
    int c4 = (g & 63) * 4;
    float t0 = 0.f, t1 = 0.f, t2 = 0.f, t3 = 0.f;
#pragma unroll
    for (int bk = 0; bk < 8; bk++) {
        t0 += sums2[bk * 4 + 0]; t1 += sums2[bk * 4 + 1];
        t2 += sums2[bk * 4 + 2]; t3 += sums2[bk * 4 + 3];
    }
    const float invn = 1.0f / (float)NN;
    float mu0 = t0 * invn, mu1 = t1 * invn;
    float v0 = t2 * invn - mu0 * mu0;
    float v1 = t3 * invn - mu1 * mu1;
    float sc0 = g2[0] * rsqrtf(v0 + EPSV), sh0 = be2[0] - mu0 * sc0;
    float sc1 = g2[1] * rsqrtf(v1 + EPSV), sh1 = be2[1] - mu1 * sc1;
    float zb0 = z2[(size_t)row * 2 + 0] * sc0 + sh0;
    float zb1 = z2[(size_t)row * 2 + 1] * sc1 + sh1;
    float4 w0 = *(const float4*)(Wd + c4);
    float4 w1 = *(const float4*)(Wd + INC + c4);
    float4 bb = *(const float4*)(bd + c4);
    float4 o;
    o.x = zb0 * w0.x + zb1 * w1.x + bb.x;
    o.y = zb0 * w0.y + zb1 * w1.y + bb.y;
    o.z = zb0 * w0.z + zb1 * w1.z + bb.z;
    o.w = zb0 * w0.w + zb1 * w1.w + bb.w;
    *(float4*)(out + (size_t)row * INC + c4) = o;
}

// ---------------- launch ----------------
static inline size_t align256(size_t x) { return (x + 255) & ~(size_t)255; }

extern "C" void kernel_launch(void* const* d_in, const int* in_sizes, int n_in,
                              void* d_out, int out_size, void* d_ws, size_t ws_size,
                              hipStream_t stream) {
    const float* x  = (const float*)d_in[0];
    const int*   ei = (const int*)d_in[1];     // [2, E] int32
    const float* W1 = (const float*)d_in[2];
    const float* b1 = (const float*)d_in[3];
    const float* g1 = (const float*)d_in[4];
    const float* be1 = (const float*)d_in[5];
    const float* W2 = (const float*)d_in[6];
    const float* b2 = (const float*)d_in[7];
    const float* g2 = (const float*)d_in[8];
    const float* be2 = (const float*)d_in[9];
    const float* Wd = (const float*)d_in[10];
    const float* bd = (const float*)d_in[11];
    float* out = (float*)d_out;

    const int* src = ei;
    const int* dst = ei + NE;

    char* ws = (char*)d_ws;
    size_t off = 0;
    int* gtail = (int*)(ws + off);      off = align256(off + NBUCK * 4);
    float* sums1 = (float*)(ws + off);  off = align256(off + 128 * 4);
    float* sums2 = (float*)(ws + off);  off = align256(off + 32 * 4);
    size_t zero_bytes = off;
    int* bbase = (int*)(ws + off);      off = align256(off + NBUCK * 4);
    int* rowptr = (int*)(ws + off);     off = align256(off + (NN + 1) * 4);
    float* dinv = (float*)(ws + off);   off = align256(off + NN * 4);
    unsigned short* Wtb = (unsigned short*)(ws + off); off = align256(off + (size_t)HID * INC * 2);
    unsigned int* pbuf = (unsigned int*)(ws + off); off = align256(off + (size_t)NBUCK * BCAP * 4 + 4096);
    int* e_src = (int*)(ws + off);      off = align256(off + (size_t)NE * 4 + 64);
    unsigned short* xw1h = (unsigned short*)(ws + off); off = align256(off + (size_t)NN * HID * 2);
    float* h1h = (float*)(ws + off);    off = align256(off + (size_t)NN * HID * 4);
    float* xw2 = (float*)(ws + off);    off = align256(off + (size_t)NN * 2 * 4);
    float* z2 = (float*)(ws + off);     off = align256(off + (size_t)NN * 2 * 4);
    (void)ws_size; (void)in_sizes; (void)n_in; (void)out_size;

    hipMemsetAsync(d_ws, 0, zero_bytes, stream);

    bin_kernel<<<BIN_GRID, 256, 0, stream>>>(src, dst, gtail, pbuf);
    bscan_kernel<<<1, 128, 0, stream>>>(gtail, bbase);
    build_kernel<<<NBUCK, 256, 0, stream>>>(pbuf, gtail, bbase, rowptr, dinv, e_src);
    wprep_kernel<<<64, 256, 0, stream>>>(W1, Wtb);
    gemm1_kernel<<<NN / G1_ROWS, 256, 0, stream>>>(x, Wtb, dinv, xw1h);
    agg1_kernel<<<2048, 256, 0, stream>>>(xw1h, rowptr, e_src, dinv, b1, h1h, sums1);
    gemm2_kernel<<<(NN + 3) / 4, 256, 0, stream>>>(h1h, sums1, g1, be1, W2, dinv, xw2);
    agg2_kernel<<<NN * 8 / 256, 256, 0, stream>>>(xw2, rowptr, e_src, dinv, b2, z2, sums2);
    decoder_kernel<<<(NN * HID) / 256, 256, 0, stream>>>(z2, sums2, g2, be2, Wd, bd, out);
}